// Round 1
// baseline (144.672 us; speedup 1.0000x reference)
//
#include <hip/hip_runtime.h>
#include <hip/hip_bf16.h>

typedef short bf16x8 __attribute__((ext_vector_type(8)));
typedef float f32x4 __attribute__((ext_vector_type(4)));

#define S 2048
#define D 64
#define NBH 24

// swizzled element offset within a [rows][64] bf16 LDS tile (16B-unit XOR, G4 recipe)
__device__ __forceinline__ int swz(int row, int unit) {  // unit = 16B unit 0..7
    return row * 64 + ((unit ^ (row & 7)) << 3);
}

// L2-normalize rows of 64 fp32 -> bf16. One wave per row, 4 rows/block.
__global__ __launch_bounds__(256) void norm_rows(const float* __restrict__ in,
                                                 __hip_bfloat16* __restrict__ out) {
    int row  = blockIdx.x * 4 + (threadIdx.x >> 6);
    int lane = threadIdx.x & 63;
    float x = in[(size_t)row * 64 + lane];
    float ss = x * x;
    #pragma unroll
    for (int m = 1; m <= 32; m <<= 1) ss += __shfl_xor(ss, m, 64);
    float y = x * rsqrtf(ss + 1e-6f);
    out[(size_t)row * 64 + lane] = __float2bfloat16(y);
}

// V [bh][s][d] fp32 -> Vt [bh][d][s] bf16 (64x64 tiles via LDS)
__global__ __launch_bounds__(256) void transpose_v(const float* __restrict__ V,
                                                   __hip_bfloat16* __restrict__ Vt) {
    __shared__ float tile[64][65];
    int bh = blockIdx.x >> 5;
    int s0 = (blockIdx.x & 31) << 6;
    int t  = threadIdx.x;
    #pragma unroll
    for (int i = 0; i < 16; ++i) {
        int idx = i * 256 + t;
        int sl = idx >> 6, d = idx & 63;
        tile[sl][d] = V[(size_t)bh * S * D + (size_t)(s0 + sl) * D + d];
    }
    __syncthreads();
    #pragma unroll
    for (int i = 0; i < 16; ++i) {
        int idx = i * 256 + t;
        int d = idx >> 6, sl = idx & 63;
        Vt[(size_t)bh * S * D + (size_t)d * S + s0 + sl] = __float2bfloat16(tile[sl][d]);
    }
}

// Main: per block = one (bh, 64-row q-tile). 4 waves, each owns 16 q-rows.
__global__ __launch_bounds__(256) void yoso_main(const __hip_bfloat16* __restrict__ Qn,
                                                 const __hip_bfloat16* __restrict__ Kn,
                                                 const __hip_bfloat16* __restrict__ Vt,
                                                 const int* __restrict__ mask,
                                                 const int* __restrict__ hlen_ptr,
                                                 float* __restrict__ out) {
    __shared__ __hip_bfloat16 Kl[64 * 64];      // [key][d], swizzled
    __shared__ __hip_bfloat16 Vl[64 * 64];      // [d][key], swizzled
    __shared__ __hip_bfloat16 Wl[4][16 * 64];   // per-wave [q][key], swizzled
    __shared__ float Ml[64];                    // key mask

    const int blk  = blockIdx.x;
    const int bh   = blk >> 5;
    const int q0   = (blk & 31) << 6;
    const int b    = bh / 12;
    const int t    = threadIdx.x;
    const int w    = t >> 6;
    const int lane = t & 63;
    const int g    = lane >> 4;
    const int c    = lane & 15;
    const float hf = (float)hlen_ptr[0];
    const size_t head_off = (size_t)bh * S * D;

    // Q A-fragments direct from global: row = q0 + w*16 + c, k(d) = g*8 + kk*32
    bf16x8 qf[2];
    {
        const __hip_bfloat16* qb = Qn + head_off + (size_t)(q0 + w * 16 + c) * D + g * 8;
        qf[0] = *(const bf16x8*)(qb);
        qf[1] = *(const bf16x8*)(qb + 32);
    }

    f32x4 xacc[4];
    #pragma unroll
    for (int i = 0; i < 4; ++i) xacc[i] = (f32x4){0.f, 0.f, 0.f, 0.f};

    for (int kt = 0; kt < S / 64; ++kt) {
        const int k0 = kt * 64;
        __syncthreads();
        // stage K tile [64 keys][64 d] bf16, 16B/thread x2
        #pragma unroll
        for (int i = 0; i < 2; ++i) {
            int chunk = i * 256 + t;
            int row = chunk >> 3, u = chunk & 7;
            int4 v = *(const int4*)(Kn + head_off + (size_t)(k0 + row) * D + u * 8);
            *(int4*)(Kl + swz(row, u)) = v;
        }
        // stage Vt tile [64 d][64 keys]
        #pragma unroll
        for (int i = 0; i < 2; ++i) {
            int chunk = i * 256 + t;
            int row = chunk >> 3, u = chunk & 7;
            int4 v = *(const int4*)(Vt + head_off + (size_t)row * S + k0 + u * 8);
            *(int4*)(Vl + swz(row, u)) = v;
        }
        if (t < 64) Ml[t] = (float)mask[b * S + k0 + t];
        __syncthreads();

        // sim = Qn @ Kn^T : 16 q-rows x 64 keys per wave
        f32x4 sacc[4];
        #pragma unroll
        for (int n0 = 0; n0 < 4; ++n0) {
            sacc[n0] = (f32x4){0.f, 0.f, 0.f, 0.f};
            #pragma unroll
            for (int kk = 0; kk < 2; ++kk) {
                bf16x8 kf = *(const bf16x8*)(Kl + swz(n0 * 16 + c, g + kk * 4));
                sacc[n0] = __builtin_amdgcn_mfma_f32_16x16x32_bf16(qf[kk], kf, sacc[n0], 0, 0, 0);
            }
        }

        // transform: w = (1 - acos(s)/pi)^h * mask_k  -> per-wave W tile (bf16)
        #pragma unroll
        for (int n0 = 0; n0 < 4; ++n0) {
            float mk = Ml[n0 * 16 + c];
            #pragma unroll
            for (int r = 0; r < 4; ++r) {
                float s = sacc[n0][r];
                s = fminf(fmaxf(s, -1.f + 1e-6f), 1.f - 1e-6f);
                float a = fabsf(s);
                // A&S 4.4.45: acos(a) ~ sqrt(1-a)*poly(a), |err| <= 6.8e-5 rad
                float p  = 1.5707288f + a * (-0.2121144f + a * (0.0742610f + a * (-0.0187293f)));
                float rr = sqrtf(1.f - a) * p;
                float tt = rr * 0.31830988618f;          // acos(|s|)/pi
                float u  = (s >= 0.f) ? (1.f - tt) : tt; // 1 - acos(s)/pi
                float wv = __builtin_amdgcn_exp2f(hf * __builtin_amdgcn_logf(u)) * mk;
                int row = 4 * g + r, col = n0 * 16 + c;
                Wl[w][row * 64 + ((((col >> 3) ^ (row & 7)) << 3) | (col & 7))] =
                    __float2bfloat16(wv);
            }
        }

        // X += W @ V : A = Wl (row=q-local c, k=key), B = Vl (col=d, k=key)
        #pragma unroll
        for (int kk = 0; kk < 2; ++kk) {
            bf16x8 af = *(const bf16x8*)(Wl[w] + swz(c, g + kk * 4));
            #pragma unroll
            for (int n0 = 0; n0 < 4; ++n0) {
                bf16x8 vf = *(const bf16x8*)(Vl + swz(n0 * 16 + c, g + kk * 4));
                xacc[n0] = __builtin_amdgcn_mfma_f32_16x16x32_bf16(af, vf, xacc[n0], 0, 0, 0);
            }
        }
    }

    // epilogue: query mask, L2-normalize each q-row, fp32 store
    #pragma unroll
    for (int r = 0; r < 4; ++r) {
        int qrow = q0 + w * 16 + 4 * g + r;
        float mq = (float)mask[b * S + qrow];
        float x[4];
        float ss = 0.f;
        #pragma unroll
        for (int n0 = 0; n0 < 4; ++n0) { x[n0] = xacc[n0][r] * mq; ss += x[n0] * x[n0]; }
        #pragma unroll
        for (int m = 1; m <= 8; m <<= 1) ss += __shfl_xor(ss, m, 64);
        float sc = rsqrtf(ss + 1e-6f);
        #pragma unroll
        for (int n0 = 0; n0 < 4; ++n0)
            out[((size_t)bh * S + qrow) * D + n0 * 16 + c] = x[n0] * sc;
    }
}

extern "C" void kernel_launch(void* const* d_in, const int* in_sizes, int n_in,
                              void* d_out, int out_size, void* d_ws, size_t ws_size,
                              hipStream_t stream) {
    const float* Q    = (const float*)d_in[0];
    const float* K    = (const float*)d_in[1];
    const float* V    = (const float*)d_in[2];
    const int*   mask = (const int*)d_in[3];
    const int*   hlen = (const int*)d_in[4];
    float*       out  = (float*)d_out;

    __hip_bfloat16* Qn = (__hip_bfloat16*)d_ws;
    __hip_bfloat16* Kn = Qn + (size_t)NBH * S * D;
    __hip_bfloat16* Vt = Kn + (size_t)NBH * S * D;

    norm_rows<<<NBH * S / 4, 256, 0, stream>>>(Q, Qn);
    norm_rows<<<NBH * S / 4, 256, 0, stream>>>(K, Kn);
    transpose_v<<<NBH * 32, 256, 0, stream>>>(V, Vt);
    yoso_main<<<NBH * 32, 256, 0, stream>>>(Qn, Kn, Vt, mask, hlen, out);
}

// Round 2
// 119.350 us; speedup vs baseline: 1.2122x; 1.2122x over previous
//
#include <hip/hip_runtime.h>
#include <hip/hip_bf16.h>

typedef short bf16x8 __attribute__((ext_vector_type(8)));
typedef float f32x16 __attribute__((ext_vector_type(16)));
typedef float f32x4  __attribute__((ext_vector_type(4)));

#define S 2048
#define D 64
#define NBH 24
#define NT (S / 64)

// swizzled element offset within a [rows][64] bf16 LDS tile (16B-unit XOR)
__device__ __forceinline__ int swz(int row, int unit) {
    return row * 64 + ((unit ^ (row & 7)) << 3);
}

#define GLOAD16(g, l) __builtin_amdgcn_global_load_lds(                      \
    (const __attribute__((address_space(1))) unsigned int*)(g),              \
    (__attribute__((address_space(3))) unsigned int*)(l), 16, 0, 0)

__device__ __forceinline__ int cvtpk_bf16(float lo, float hi) {
    int r;
    asm("v_cvt_pk_bf16_f32 %0, %1, %2" : "=v"(r) : "v"(lo), "v"(hi));
    return r;
}

// L2-normalize rows of 64 fp32 -> bf16. One wave per row, 4 rows/block.
__global__ __launch_bounds__(256) void norm_rows(const float* __restrict__ in,
                                                 __hip_bfloat16* __restrict__ out) {
    int row  = blockIdx.x * 4 + (threadIdx.x >> 6);
    int lane = threadIdx.x & 63;
    float x = in[(size_t)row * 64 + lane];
    float ss = x * x;
    #pragma unroll
    for (int m = 1; m <= 32; m <<= 1) ss += __shfl_xor(ss, m, 64);
    float y = x * rsqrtf(ss + 1e-6f);
    out[(size_t)row * 64 + lane] = __float2bfloat16(y);
}

// V [bh][s][d] fp32 -> Vt [bh][d][s] bf16, key-mask folded in: Vt = (m_k * V)^T
__global__ __launch_bounds__(256) void transpose_v(const float* __restrict__ V,
                                                   const int* __restrict__ mask,
                                                   __hip_bfloat16* __restrict__ Vt) {
    __shared__ float tile[64][65];
    int bh = blockIdx.x >> 5;
    int b  = bh / 12;
    int s0 = (blockIdx.x & 31) << 6;
    int t  = threadIdx.x;
    #pragma unroll
    for (int i = 0; i < 16; ++i) {
        int idx = i * 256 + t;
        int sl = idx >> 6, d = idx & 63;
        float mv = (float)mask[b * S + s0 + sl];
        tile[sl][d] = V[(size_t)bh * S * D + (size_t)(s0 + sl) * D + d] * mv;
    }
    __syncthreads();
    #pragma unroll
    for (int i = 0; i < 16; ++i) {
        int idx = i * 256 + t;
        int d = idx >> 6, sl = idx & 63;
        Vt[(size_t)bh * S * D + (size_t)d * S + s0 + sl] = __float2bfloat16(tile[sl][d]);
    }
}

// Main: block = (bh, 64 q-rows). 4 waves: w>>1 = q-half (32 q), w&1 = key-half (32 k).
// Swapped QK^T (mfma(K,Q)) -> P register-local per q-col -> cvt_pk+permlane32_swap
// -> PV A-frags. Partial X over key-halves reduced via LDS at the end.
__global__ __launch_bounds__(256) void yoso_main(const __hip_bfloat16* __restrict__ Qn,
                                                 const __hip_bfloat16* __restrict__ Kn,
                                                 const __hip_bfloat16* __restrict__ Vt,
                                                 const int* __restrict__ mask,
                                                 const int* __restrict__ hlen_ptr,
                                                 float* __restrict__ out) {
    __shared__ __hip_bfloat16 lds[2][2][64 * 64];  // [buf][0=K [key][d], 1=V [d][key]]

    const int blk  = blockIdx.x;
    const int bh   = blk >> 5;
    const int q0   = (blk & 31) << 6;
    const int b    = bh / 12;
    const int t    = threadIdx.x;
    const int w    = t >> 6;
    const int lane = t & 63;
    const int h    = lane >> 5;
    const int c31  = lane & 31;
    const int kh   = w & 1;   // key half
    const int qh   = w >> 1;  // q half
    const int hcode = hlen_ptr[0];
    const size_t head = (size_t)bh * S * D;

    // staging geometry: chunk c covers rows 8c..8c+7; lane -> (row, pre-swizzled unit)
    const int srow  = lane >> 3;
    const int sunit = (lane & 7) ^ (srow & 7);
    const char* Kg = (const char*)(Kn + head);  // row (key) stride 128 B
    const char* Vg = (const char*)(Vt + head);  // row (d) stride 4096 B

    // Q B-fragments (held all loop): B[k=d][col=q], d = 16*kd + 8*h + j
    bf16x8 qf[4];
    {
        const __hip_bfloat16* qp = Qn + head + (size_t)(q0 + qh * 32 + c31) * D + h * 8;
        qf[0] = *(const bf16x8*)(qp);
        qf[1] = *(const bf16x8*)(qp + 16);
        qf[2] = *(const bf16x8*)(qp + 32);
        qf[3] = *(const bf16x8*)(qp + 48);
    }

    f32x16 xacc0 = {0,0,0,0,0,0,0,0,0,0,0,0,0,0,0,0};
    f32x16 xacc1 = {0,0,0,0,0,0,0,0,0,0,0,0,0,0,0,0};

    auto STAGE = [&](int buf, int kt) {
        const int k0 = kt * 64;
        char* Kl = (char*)&lds[buf][0][0];
        char* Vl = (char*)&lds[buf][1][0];
        const char* kb = Kg + (size_t)k0 * 128;
        const char* vb = Vg + (size_t)k0 * 2;
        const int koff = (8 * w + srow) * 128 + sunit * 16;
        const int voff = (8 * w + srow) * 4096 + sunit * 16;
        GLOAD16(kb + koff,             Kl + w * 1024);
        GLOAD16(kb + koff + 4096,      Kl + (w + 4) * 1024);
        GLOAD16(vb + voff,             Vl + w * 1024);
        GLOAD16(vb + voff + 32 * 4096, Vl + (w + 4) * 1024);
    };

    STAGE(0, 0);
    __syncthreads();
    int cur = 0;

    for (int kt = 0; kt < NT; ++kt) {
        if (kt + 1 < NT) STAGE(cur ^ 1, kt + 1);  // prefetch overlaps compute

        const __hip_bfloat16* Kc = &lds[cur][0][0];
        const __hip_bfloat16* Vc = &lds[cur][1][0];

        // S^T = K_half @ Q^T : C[key][q], col=l&31=q, row=crow(r,h)=key
        f32x16 sacc = {0,0,0,0,0,0,0,0,0,0,0,0,0,0,0,0};
        #pragma unroll
        for (int kd = 0; kd < 4; ++kd) {
            bf16x8 kf = *(const bf16x8*)(Kc + swz(kh * 32 + c31, 2 * kd + h));
            sacc = __builtin_amdgcn_mfma_f32_32x32x16_bf16(kf, qf[kd], sacc, 0, 0, 0);
        }

        // transform: u = 1 - acos(s)/pi (A&S poly, 1/pi folded into coeffs)
        float uu[16];
        #pragma unroll
        for (int r = 0; r < 16; ++r) {
            float s = sacc[r];
            float a = fminf(fabsf(s), 0.999999f);
            float p = 0.4999741f + a * (-0.0675176f + a * (0.0236372f + a * (-0.00596128f)));
            float tt = sqrtf(1.0f - a) * p;                 // acos(|s|)/pi
            uu[r] = (s >= 0.0f) ? (1.0f - tt) : tt;
        }
        float wv[16];
        if (hcode == 9) {
            #pragma unroll
            for (int r = 0; r < 16; ++r) {
                float u2 = uu[r] * uu[r];
                float u4 = u2 * u2;
                float u8 = u4 * u4;
                wv[r] = u8 * uu[r];
            }
        } else {
            float hf = (float)hcode;
            #pragma unroll
            for (int r = 0; r < 16; ++r)
                wv[r] = __builtin_amdgcn_exp2f(hf * __builtin_amdgcn_logf(uu[r]));
        }

        // pack to bf16 + permlane32_swap -> PV A-fragments (keys lane-local per q-row)
        int u_[8];
        #pragma unroll
        for (int i = 0; i < 8; ++i) u_[i] = cvtpk_bf16(wv[2 * i], wv[2 * i + 1]);
        // swap(u_lo, u_hi): u_lo -> word(j=2i), u_hi -> word(j=2i+4)
        asm("v_permlane32_swap_b32 %0, %1" : "+v"(u_[0]), "+v"(u_[2]));
        asm("v_permlane32_swap_b32 %0, %1" : "+v"(u_[1]), "+v"(u_[3]));
        asm("v_permlane32_swap_b32 %0, %1" : "+v"(u_[4]), "+v"(u_[6]));
        asm("v_permlane32_swap_b32 %0, %1" : "+v"(u_[5]), "+v"(u_[7]));
        union { int i[4]; bf16x8 v; } f0, f1;
        f0.i[0] = u_[0]; f0.i[1] = u_[1]; f0.i[2] = u_[2]; f0.i[3] = u_[3];
        f1.i[0] = u_[4]; f1.i[1] = u_[5]; f1.i[2] = u_[6]; f1.i[3] = u_[7];

        // X_partial += P_half @ V_half : A[row=q][k=key], B[k=key][col=d]
        #pragma unroll
        for (int kb2 = 0; kb2 < 2; ++kb2) {
            bf16x8 af = (kb2 == 0) ? f0.v : f1.v;
            bf16x8 vf0 = *(const bf16x8*)(Vc + swz(c31,      kh * 4 + kb2 * 2 + h));
            bf16x8 vf1 = *(const bf16x8*)(Vc + swz(32 + c31, kh * 4 + kb2 * 2 + h));
            xacc0 = __builtin_amdgcn_mfma_f32_32x32x16_bf16(af, vf0, xacc0, 0, 0, 0);
            xacc1 = __builtin_amdgcn_mfma_f32_32x32x16_bf16(af, vf1, xacc1, 0, 0, 0);
        }

        __syncthreads();
        cur ^= 1;
    }

    // cross-wave reduce over key-halves, then L2-normalize + store (even waves)
    float* red = (float*)&lds[0][0][0];  // 4096 floats = 16 KiB
    if (kh == 1) {
        #pragma unroll
        for (int r = 0; r < 16; ++r) {
            int q = (r & 3) + 8 * (r >> 2) + 4 * h;
            red[qh * 2048 + q * 64 + c31]      = xacc0[r];
            red[qh * 2048 + q * 64 + 32 + c31] = xacc1[r];
        }
    }
    __syncthreads();
    if (kh == 0) {
        #pragma unroll
        for (int r = 0; r < 16; ++r) {
            int q = (r & 3) + 8 * (r >> 2) + 4 * h;
            float x0 = xacc0[r] + red[qh * 2048 + q * 64 + c31];
            float x1 = xacc1[r] + red[qh * 2048 + q * 64 + 32 + c31];
            int qg = q0 + qh * 32 + q;
            float mq = (float)mask[b * S + qg];
            x0 *= mq; x1 *= mq;
            float ss = x0 * x0 + x1 * x1;
            #pragma unroll
            for (int m = 1; m <= 16; m <<= 1) ss += __shfl_xor(ss, m, 64);
            float sc = rsqrtf(ss + 1e-6f);
            float* op = out + ((size_t)bh * S + qg) * D;
            op[c31]      = x0 * sc;
            op[32 + c31] = x1 * sc;
        }
    }
}

extern "C" void kernel_launch(void* const* d_in, const int* in_sizes, int n_in,
                              void* d_out, int out_size, void* d_ws, size_t ws_size,
                              hipStream_t stream) {
    const float* Q    = (const float*)d_in[0];
    const float* K    = (const float*)d_in[1];
    const float* V    = (const float*)d_in[2];
    const int*   mask = (const int*)d_in[3];
    const int*   hlen = (const int*)d_in[4];
    float*       out  = (float*)d_out;

    __hip_bfloat16* Qn = (__hip_bfloat16*)d_ws;
    __hip_bfloat16* Kn = Qn + (size_t)NBH * S * D;
    __hip_bfloat16* Vt = Kn + (size_t)NBH * S * D;

    norm_rows<<<NBH * S / 4, 256, 0, stream>>>(Q, Qn);
    norm_rows<<<NBH * S / 4, 256, 0, stream>>>(K, Kn);
    transpose_v<<<NBH * 32, 256, 0, stream>>>(V, mask, Vt);
    yoso_main<<<NBH * 32, 256, 0, stream>>>(Qn, Kn, Vt, mask, hlen, out);
}

// Round 3
// 92.896 us; speedup vs baseline: 1.5574x; 1.2848x over previous
//
#include <hip/hip_runtime.h>
#include <hip/hip_bf16.h>

typedef short bf16x8 __attribute__((ext_vector_type(8)));
typedef float f32x16 __attribute__((ext_vector_type(16)));

#define S 2048
#define D 64
#define NBH 24

// swizzled element offset within a [rows][64] bf16 LDS tile (16B-unit XOR)
__device__ __forceinline__ int swz(int row, int unit) {
    return row * 64 + ((unit ^ (row & 7)) << 3);
}

#define GLOAD16(g, l) __builtin_amdgcn_global_load_lds(                      \
    (const __attribute__((address_space(1))) unsigned int*)(g),              \
    (__attribute__((address_space(3))) unsigned int*)(l), 16, 0, 0)

__device__ __forceinline__ int cvtpk_bf16(float lo, float hi) {
    int r;
    asm("v_cvt_pk_bf16_f32 %0, %1, %2" : "=v"(r) : "v"(lo), "v"(hi));
    return r;
}

// L2-normalize rows of Q and K (fp32 -> bf16) in one launch. 4 rows/block.
__global__ __launch_bounds__(256) void norm_qk(const float* __restrict__ Q,
                                               const float* __restrict__ K,
                                               __hip_bfloat16* __restrict__ Qn,
                                               __hip_bfloat16* __restrict__ Kn) {
    const int nb   = NBH * S / 4;
    int half = blockIdx.x >= nb;
    int row  = (blockIdx.x - half * nb) * 4 + (threadIdx.x >> 6);
    int lane = threadIdx.x & 63;
    const float* in = half ? K : Q;
    __hip_bfloat16* out = half ? Kn : Qn;
    float x = in[(size_t)row * 64 + lane];
    float ss = x * x;
    #pragma unroll
    for (int m = 1; m <= 32; m <<= 1) ss += __shfl_xor(ss, m, 64);
    float y = x * rsqrtf(ss + 1e-6f);
    out[(size_t)row * 64 + lane] = __float2bfloat16(y);
}

// V [bh][s][d] fp32 -> Vt [bh][d][s] bf16, key-mask folded in: Vt = (m_k * V)^T
__global__ __launch_bounds__(256) void transpose_v(const float* __restrict__ V,
                                                   const int* __restrict__ mask,
                                                   __hip_bfloat16* __restrict__ Vt) {
    __shared__ float tile[64][65];
    int bh = blockIdx.x >> 5;
    int b  = bh / 12;
    int s0 = (blockIdx.x & 31) << 6;
    int t  = threadIdx.x;
    #pragma unroll
    for (int i = 0; i < 16; ++i) {
        int idx = i * 256 + t;
        int sl = idx >> 6, d = idx & 63;
        float mv = (float)mask[b * S + s0 + sl];
        tile[sl][d] = V[(size_t)bh * S * D + (size_t)(s0 + sl) * D + d] * mv;
    }
    __syncthreads();
    #pragma unroll
    for (int i = 0; i < 16; ++i) {
        int idx = i * 256 + t;
        int d = idx >> 6, sl = idx & 63;
        Vt[(size_t)bh * S * D + (size_t)d * S + s0 + sl] = __float2bfloat16(tile[sl][d]);
    }
}

// Main. PARTIAL: block = (bh, 64 q-rows, key-half of 1024) -> raw partial X (1536 blocks).
// else: block = (bh, 64 q-rows), full keys, fused mask+normalize (768 blocks).
// 4 waves: w>>1 = q-half (32 q), w&1 = key-half of each 64-key tile.
template<bool PARTIAL>
__global__ __launch_bounds__(256) void yoso_main(const __hip_bfloat16* __restrict__ Qn,
                                                 const __hip_bfloat16* __restrict__ Kn,
                                                 const __hip_bfloat16* __restrict__ Vt,
                                                 const int* __restrict__ mask,
                                                 const int* __restrict__ hlen_ptr,
                                                 float* __restrict__ outp) {
    __shared__ __hip_bfloat16 lds[2][2][64 * 64];  // [buf][0=K [key][d], 1=V [d][key]]

    const int blk = blockIdx.x;
    int bh, q0, kbase;
    if (PARTIAL) { bh = blk >> 6; q0 = ((blk >> 1) & 31) << 6; kbase = (blk & 1) << 10; }
    else         { bh = blk >> 5; q0 = (blk & 31) << 6;        kbase = 0; }
    const int NTt = PARTIAL ? (S / 128) : (S / 64);

    const int b    = bh / 12;
    const int t    = threadIdx.x;
    const int w    = t >> 6;
    const int lane = t & 63;
    const int h    = lane >> 5;
    const int c31  = lane & 31;
    const int kh   = w & 1;   // key half within tile
    const int qh   = w >> 1;  // q half
    const int hcode = hlen_ptr[0];
    const size_t head = (size_t)bh * S * D;

    // staging geometry: lane -> (row, pre-swizzled 16B unit)
    const int srow  = lane >> 3;
    const int sunit = (lane & 7) ^ (srow & 7);
    const char* Kg = (const char*)(Kn + head);  // row (key) stride 128 B
    const char* Vg = (const char*)(Vt + head);  // row (d) stride 4096 B

    // Q B-fragments (held all loop): B[k=d][col=q]
    bf16x8 qf[4];
    {
        const __hip_bfloat16* qp = Qn + head + (size_t)(q0 + qh * 32 + c31) * D + h * 8;
        qf[0] = *(const bf16x8*)(qp);
        qf[1] = *(const bf16x8*)(qp + 16);
        qf[2] = *(const bf16x8*)(qp + 32);
        qf[3] = *(const bf16x8*)(qp + 48);
    }

    f32x16 xacc0 = {0,0,0,0,0,0,0,0,0,0,0,0,0,0,0,0};
    f32x16 xacc1 = {0,0,0,0,0,0,0,0,0,0,0,0,0,0,0,0};

    auto STAGE = [&](int buf, int k0) {
        char* Kl = (char*)&lds[buf][0][0];
        char* Vl = (char*)&lds[buf][1][0];
        const char* kb = Kg + (size_t)k0 * 128;
        const char* vb = Vg + (size_t)k0 * 2;
        const int koff = (8 * w + srow) * 128 + sunit * 16;
        const int voff = (8 * w + srow) * 4096 + sunit * 16;
        GLOAD16(kb + koff,             Kl + w * 1024);
        GLOAD16(kb + koff + 4096,      Kl + (w + 4) * 1024);
        GLOAD16(vb + voff,             Vl + w * 1024);
        GLOAD16(vb + voff + 32 * 4096, Vl + (w + 4) * 1024);
    };

    STAGE(0, kbase);
    __syncthreads();
    int cur = 0;

    for (int kt = 0; kt < NTt; ++kt) {
        if (kt + 1 < NTt) STAGE(cur ^ 1, kbase + (kt + 1) * 64);  // prefetch

        const __hip_bfloat16* Kc = &lds[cur][0][0];
        const __hip_bfloat16* Vc = &lds[cur][1][0];

        // S^T = K_half @ Q^T : C[key][q], col=lane&31=q, row=crow(r,h)=key
        f32x16 sacc = {0,0,0,0,0,0,0,0,0,0,0,0,0,0,0,0};
        #pragma unroll
        for (int kd = 0; kd < 4; ++kd) {
            bf16x8 kf = *(const bf16x8*)(Kc + swz(kh * 32 + c31, 2 * kd + h));
            sacc = __builtin_amdgcn_mfma_f32_32x32x16_bf16(kf, qf[kd], sacc, 0, 0, 0);
        }

        // w = (1 - acos(s)/pi)^h via odd-identity: x = 0.5 + copysign(0.5 - acos(|s|)/pi, s)
        float wv[16];
        #pragma unroll
        for (int r = 0; r < 16; ++r) {
            float s = sacc[r];
            float a = fminf(fabsf(s), 0.999999f);
            float p = 0.4999741f + a * (-0.0675176f + a * (0.0236372f + a * (-0.00596128f)));
            float tt = __builtin_amdgcn_sqrtf(1.0f - a) * p;   // acos(|s|)/pi, raw v_sqrt
            float x  = 0.5f + __builtin_copysignf(0.5f - tt, s);
            if (hcode == 9) {
                float x2 = x * x;
                float x4 = x2 * x2;
                wv[r] = x4 * x4 * x;
            } else {
                wv[r] = __builtin_amdgcn_exp2f((float)hcode * __builtin_amdgcn_logf(x));
            }
        }

        // pack to bf16 + permlane32_swap -> PV A-fragments (keys lane-local per q-row)
        int u_[8];
        #pragma unroll
        for (int i = 0; i < 8; ++i) u_[i] = cvtpk_bf16(wv[2 * i], wv[2 * i + 1]);
        asm("v_permlane32_swap_b32 %0, %1" : "+v"(u_[0]), "+v"(u_[2]));
        asm("v_permlane32_swap_b32 %0, %1" : "+v"(u_[1]), "+v"(u_[3]));
        asm("v_permlane32_swap_b32 %0, %1" : "+v"(u_[4]), "+v"(u_[6]));
        asm("v_permlane32_swap_b32 %0, %1" : "+v"(u_[5]), "+v"(u_[7]));
        union { int i[4]; bf16x8 v; } f0, f1;
        f0.i[0] = u_[0]; f0.i[1] = u_[1]; f0.i[2] = u_[2]; f0.i[3] = u_[3];
        f1.i[0] = u_[4]; f1.i[1] = u_[5]; f1.i[2] = u_[6]; f1.i[3] = u_[7];

        // X_partial += P_half @ V_half
        #pragma unroll
        for (int kb2 = 0; kb2 < 2; ++kb2) {
            bf16x8 af = (kb2 == 0) ? f0.v : f1.v;
            bf16x8 vf0 = *(const bf16x8*)(Vc + swz(c31,      kh * 4 + kb2 * 2 + h));
            bf16x8 vf1 = *(const bf16x8*)(Vc + swz(32 + c31, kh * 4 + kb2 * 2 + h));
            xacc0 = __builtin_amdgcn_mfma_f32_32x32x16_bf16(af, vf0, xacc0, 0, 0, 0);
            xacc1 = __builtin_amdgcn_mfma_f32_32x32x16_bf16(af, vf1, xacc1, 0, 0, 0);
        }

        __syncthreads();
        cur ^= 1;
    }

    // cross-wave reduce over tile-key-halves
    float* red = (float*)&lds[0][0][0];  // 4096 floats
    if (kh == 1) {
        #pragma unroll
        for (int r = 0; r < 16; ++r) {
            int q = (r & 3) + 8 * (r >> 2) + 4 * h;
            red[qh * 2048 + q * 64 + c31]      = xacc0[r];
            red[qh * 2048 + q * 64 + 32 + c31] = xacc1[r];
        }
    }
    __syncthreads();
    if (kh == 0) {
        #pragma unroll
        for (int r = 0; r < 16; ++r) {
            int q = (r & 3) + 8 * (r >> 2) + 4 * h;
            float x0 = xacc0[r] + red[qh * 2048 + q * 64 + c31];
            float x1 = xacc1[r] + red[qh * 2048 + q * 64 + 32 + c31];
            int qg = q0 + qh * 32 + q;
            if (PARTIAL) {
                float* pp = outp + ((size_t)((blk & 1) * NBH + bh) * S + qg) * D;
                pp[c31]      = x0;
                pp[32 + c31] = x1;
            } else {
                float mq = (float)mask[b * S + qg];
                x0 *= mq; x1 *= mq;
                float ss = x0 * x0 + x1 * x1;
                #pragma unroll
                for (int m = 1; m <= 16; m <<= 1) ss += __shfl_xor(ss, m, 64);
                float sc = rsqrtf(ss + 1e-6f);
                float* op = outp + ((size_t)bh * S + qg) * D;
                op[c31]      = x0 * sc;
                op[32 + c31] = x1 * sc;
            }
        }
    }
}

// Pass 2: sum key-half partials, apply query mask, L2-normalize, store fp32.
__global__ __launch_bounds__(256) void combine_norm(const float* __restrict__ P,
                                                    const int* __restrict__ mask,
                                                    float* __restrict__ out) {
    size_t row = (size_t)blockIdx.x * 4 + (threadIdx.x >> 6);
    int lane = threadIdx.x & 63;
    size_t i = row * 64 + lane;
    float x = P[i] + P[(size_t)NBH * S * D + i];
    int bh = (int)(row >> 11);          // S = 2048
    int sidx = (int)(row & 2047);
    int b = bh / 12;
    x *= (float)mask[b * S + sidx];
    float ss = x * x;
    #pragma unroll
    for (int m = 1; m <= 32; m <<= 1) ss += __shfl_xor(ss, m, 64);
    out[i] = x * rsqrtf(ss + 1e-6f);
}

extern "C" void kernel_launch(void* const* d_in, const int* in_sizes, int n_in,
                              void* d_out, int out_size, void* d_ws, size_t ws_size,
                              hipStream_t stream) {
    const float* Q    = (const float*)d_in[0];
    const float* K    = (const float*)d_in[1];
    const float* V    = (const float*)d_in[2];
    const int*   mask = (const int*)d_in[3];
    const int*   hlen = (const int*)d_in[4];
    float*       out  = (float*)d_out;

    __hip_bfloat16* Qn = (__hip_bfloat16*)d_ws;
    __hip_bfloat16* Kn = Qn + (size_t)NBH * S * D;
    __hip_bfloat16* Vt = Kn + (size_t)NBH * S * D;
    float* Pbuf = (float*)((char*)d_ws + 3ull * NBH * S * D * 2);  // 2x partials fp32

    const size_t ws_need = 3ull * NBH * S * D * 2 + 2ull * NBH * S * D * 4;

    norm_qk<<<2 * NBH * S / 4, 256, 0, stream>>>(Q, K, Qn, Kn);
    transpose_v<<<NBH * 32, 256, 0, stream>>>(V, mask, Vt);
    if (ws_size >= ws_need) {
        yoso_main<true><<<NBH * 64, 256, 0, stream>>>(Qn, Kn, Vt, mask, hlen, Pbuf);
        combine_norm<<<NBH * S / 4, 256, 0, stream>>>(Pbuf, mask, out);
    } else {
        yoso_main<false><<<NBH * 32, 256, 0, stream>>>(Qn, Kn, Vt, mask, hlen, out);
    }
}

// Round 4
// 89.161 us; speedup vs baseline: 1.6226x; 1.0419x over previous
//
#include <hip/hip_runtime.h>
#include <hip/hip_bf16.h>

typedef short bf16x8 __attribute__((ext_vector_type(8)));
typedef float f32x16 __attribute__((ext_vector_type(16)));
typedef float f32x2  __attribute__((ext_vector_type(2)));

#define S 2048
#define D 64
#define NBH 24

#define GLOAD16(g, l) __builtin_amdgcn_global_load_lds(                      \
    (const __attribute__((address_space(1))) unsigned int*)(g),              \
    (__attribute__((address_space(3))) unsigned int*)(l), 16, 0, 0)

__device__ __forceinline__ int cvtpk_bf16(float lo, float hi) {
    int r;
    asm("v_cvt_pk_bf16_f32 %0, %1, %2" : "=v"(r) : "v"(lo), "v"(hi));
    return r;
}

// L2-normalize rows of Q and K (fp32 -> bf16) in one launch. 4 rows/block.
__global__ __launch_bounds__(256) void norm_qk(const float* __restrict__ Q,
                                               const float* __restrict__ K,
                                               __hip_bfloat16* __restrict__ Qn,
                                               __hip_bfloat16* __restrict__ Kn) {
    const int nb   = NBH * S / 4;
    int half = blockIdx.x >= nb;
    int row  = (blockIdx.x - half * nb) * 4 + (threadIdx.x >> 6);
    int lane = threadIdx.x & 63;
    const float* in = half ? K : Q;
    __hip_bfloat16* out = half ? Kn : Qn;
    float x = in[(size_t)row * 64 + lane];
    float ss = x * x;
    #pragma unroll
    for (int m = 1; m <= 32; m <<= 1) ss += __shfl_xor(ss, m, 64);
    float y = x * rsqrtf(ss + 1e-6f);
    out[(size_t)row * 64 + lane] = __float2bfloat16(y);
}

// V [bh][s][d] fp32 -> Vt [bh][d][s] bf16, key-mask folded in: Vt = (m_k * V)^T
__global__ __launch_bounds__(256) void transpose_v(const float* __restrict__ V,
                                                   const int* __restrict__ mask,
                                                   __hip_bfloat16* __restrict__ Vt) {
    __shared__ float tile[64][65];
    int bh = blockIdx.x >> 5;
    int b  = bh / 12;
    int s0 = (blockIdx.x & 31) << 6;
    int t  = threadIdx.x;
    #pragma unroll
    for (int i = 0; i < 16; ++i) {
        int idx = i * 256 + t;
        int sl = idx >> 6, d = idx & 63;
        float mv = (float)mask[b * S + s0 + sl];
        tile[sl][d] = V[(size_t)bh * S * D + (size_t)(s0 + sl) * D + d] * mv;
    }
    __syncthreads();
    #pragma unroll
    for (int i = 0; i < 16; ++i) {
        int idx = i * 256 + t;
        int d = idx >> 6, sl = idx & 63;
        Vt[(size_t)bh * S * D + (size_t)d * S + s0 + sl] = __float2bfloat16(tile[sl][d]);
    }
}

// Main. PARTIAL: block = (bh, 64 q-rows, key-half of 1024) -> raw partial X (1536 blocks).
// 4 waves: w>>1 = q-half (32 q), w&1 = key-half of each 64-key tile.
// LDS tiles [64 rows][8 x 16B units], unit placement slot(row,u) =
//   u ^ (row&7) ^ (row>>3) ^ ((u&1)<<2)  -- conflict-free for b128 reads under
// both consecutive-8 and stride-8 lane phasing; stage applies the inverse on
// the global source address (global_load_lds writes linearly, G21).
template<bool PARTIAL>
__global__ __launch_bounds__(256) void yoso_main(const __hip_bfloat16* __restrict__ Qn,
                                                 const __hip_bfloat16* __restrict__ Kn,
                                                 const __hip_bfloat16* __restrict__ Vt,
                                                 const int* __restrict__ mask,
                                                 const int* __restrict__ hlen_ptr,
                                                 float* __restrict__ outp) {
    __shared__ char lds[2][16384];   // per buf: [0,8192)=K tile, [8192,16384)=V tile

    const int blk = blockIdx.x;
    int bh, q0, kbase;
    if (PARTIAL) { bh = blk >> 6; q0 = ((blk >> 1) & 31) << 6; kbase = (blk & 1) << 10; }
    else         { bh = blk >> 5; q0 = (blk & 31) << 6;        kbase = 0; }
    const int NTt = PARTIAL ? (S / 128) : (S / 64);   // even

    const int b    = bh / 12;
    const int t    = threadIdx.x;
    const int w    = t >> 6;
    const int lane = t & 63;
    const int h    = lane >> 5;
    const int c31  = lane & 31;
    const int kh   = w & 1;
    const int qh   = w >> 1;
    const int hcode = hlen_ptr[0];
    const size_t head = (size_t)bh * S * D;

    // ---- staging source offsets (inverse swizzle on global address) ----
    const int s_  = lane & 7;
    const int r3l = lane >> 3;
    const int e1  = s_ ^ r3l ^ w;
    const int u1  = e1 ^ ((e1 & 1) << 2);
    const int u2  = u1 ^ 4;
    const int kgo1 = (8 * w + r3l) * 128 + u1 * 16;
    const int kgo2 = (8 * w + r3l + 32) * 128 + u2 * 16;
    const int vgo1 = (8 * w + r3l) * 4096 + u1 * 16;
    const int vgo2 = (8 * w + r3l + 32) * 4096 + u2 * 16;
    const char* Kg = (const char*)(Kn + head);   // key-row stride 128 B
    const char* Vg = (const char*)(Vt + head);   // d-row stride 4096 B

    // ---- LDS read offsets (loop-invariant; imm-offset handles buf/region) ----
    char* ldsc = &lds[0][0];
    const int krow = kh * 32 + c31;
    const int kb3  = (krow & 7) ^ (krow >> 3) ^ (h << 2) ^ h;
    int koffs[4];
    #pragma unroll
    for (int kd = 0; kd < 4; ++kd)
        koffs[kd] = krow * 128 + ((2 * kd) ^ kb3) * 16;
    const int vb3 = (c31 & 7) ^ (c31 >> 3) ^ (h << 2) ^ h ^ (kh << 2);
    int voffs[2][2];
    #pragma unroll
    for (int kb2 = 0; kb2 < 2; ++kb2) {
        voffs[kb2][0] = c31 * 128        + (((kb2 << 1) ^ vb3)) * 16     + 8192;
        voffs[kb2][1] = (32 + c31) * 128 + (((kb2 << 1) ^ vb3 ^ 4)) * 16 + 8192;
    }

    // Q B-fragments (held all loop)
    bf16x8 qf[4];
    {
        const __hip_bfloat16* qp = Qn + head + (size_t)(q0 + qh * 32 + c31) * D + h * 8;
        qf[0] = *(const bf16x8*)(qp);
        qf[1] = *(const bf16x8*)(qp + 16);
        qf[2] = *(const bf16x8*)(qp + 32);
        qf[3] = *(const bf16x8*)(qp + 48);
    }

    const f32x16 z16 = {0,0,0,0,0,0,0,0,0,0,0,0,0,0,0,0};
    f32x16 xacc0 = z16, xacc1 = z16;

    const bool  p9 = (hcode == 9);
    const float hf = (float)hcode;

    auto STAGE = [&](int buf, int k0) {
        const char* kb = Kg + (size_t)k0 * 128;
        const char* vb = Vg + (size_t)k0 * 2;
        char* Kl = ldsc + buf * 16384;
        char* Vl = Kl + 8192;
        GLOAD16(kb + kgo1, Kl + w * 1024);
        GLOAD16(kb + kgo2, Kl + (w + 4) * 1024);
        GLOAD16(vb + vgo1, Vl + w * 1024);
        GLOAD16(vb + vgo2, Vl + (w + 4) * 1024);
    };

    auto COMPUTE = [&](int buf) {
        const char* base = ldsc + buf * 16384;
        // S^T = K_half @ Q^T : col=lane&31=q, row=crow(r,h)=key
        f32x16 sacc = __builtin_amdgcn_mfma_f32_32x32x16_bf16(
            *(const bf16x8*)(base + koffs[0]), qf[0], z16, 0, 0, 0);
        #pragma unroll
        for (int kd = 1; kd < 4; ++kd)
            sacc = __builtin_amdgcn_mfma_f32_32x32x16_bf16(
                *(const bf16x8*)(base + koffs[kd]), qf[kd], sacc, 0, 0, 0);

        // w = x^h, x = 0.5 + copysign(0.5 - sqrt(z) q(z), s), z = 1-|s|  (packed f32)
        int u_[8];
        #pragma unroll
        for (int i = 0; i < 8; ++i) {
            f32x2 sv = { sacc[2 * i], sacc[2 * i + 1] };
            f32x2 zz = { fmaxf(1.0f - fabsf(sv.x), 0.0f),
                         fmaxf(1.0f - fabsf(sv.y), 0.0f) };
            f32x2 qq = (f32x2){0.00596128f, 0.00596128f};
            qq = qq * zz + (f32x2){0.00575336f, 0.00575336f};
            qq = qq * zz + (f32x2){0.03812704f, 0.03812704f};
            qq = qq * zz + (f32x2){0.4501324f,  0.4501324f};
            f32x2 rt = { __builtin_amdgcn_sqrtf(zz.x), __builtin_amdgcn_sqrtf(zz.y) };
            f32x2 tp = (f32x2){0.5f, 0.5f} - qq * rt;   // 0.5 - acos(|s|)/pi
            f32x2 xs = { 0.5f + __builtin_copysignf(tp.x, sv.x),
                         0.5f + __builtin_copysignf(tp.y, sv.y) };
            f32x2 wv;
            if (p9) {
                f32x2 x2 = xs * xs;
                f32x2 x4 = x2 * x2;
                wv = x4 * x4 * xs;
            } else {
                wv.x = __builtin_amdgcn_exp2f(hf * __builtin_amdgcn_logf(xs.x));
                wv.y = __builtin_amdgcn_exp2f(hf * __builtin_amdgcn_logf(xs.y));
            }
            u_[i] = cvtpk_bf16(wv.x, wv.y);
        }
        asm("v_permlane32_swap_b32 %0, %1" : "+v"(u_[0]), "+v"(u_[2]));
        asm("v_permlane32_swap_b32 %0, %1" : "+v"(u_[1]), "+v"(u_[3]));
        asm("v_permlane32_swap_b32 %0, %1" : "+v"(u_[4]), "+v"(u_[6]));
        asm("v_permlane32_swap_b32 %0, %1" : "+v"(u_[5]), "+v"(u_[7]));
        union { int i[4]; bf16x8 v; } f0, f1;
        f0.i[0] = u_[0]; f0.i[1] = u_[1]; f0.i[2] = u_[2]; f0.i[3] = u_[3];
        f1.i[0] = u_[4]; f1.i[1] = u_[5]; f1.i[2] = u_[6]; f1.i[3] = u_[7];

        // X_partial += P_half @ V_half
        #pragma unroll
        for (int kb2 = 0; kb2 < 2; ++kb2) {
            bf16x8 af  = (kb2 == 0) ? f0.v : f1.v;
            bf16x8 vf0 = *(const bf16x8*)(base + voffs[kb2][0]);
            bf16x8 vf1 = *(const bf16x8*)(base + voffs[kb2][1]);
            xacc0 = __builtin_amdgcn_mfma_f32_32x32x16_bf16(af, vf0, xacc0, 0, 0, 0);
            xacc1 = __builtin_amdgcn_mfma_f32_32x32x16_bf16(af, vf1, xacc1, 0, 0, 0);
        }
    };

    STAGE(0, kbase);
    __syncthreads();

    for (int kt = 0; kt < NTt; kt += 2) {
        if (kt + 1 < NTt) STAGE(1, kbase + (kt + 1) * 64);
        COMPUTE(0);
        __syncthreads();
        if (kt + 2 < NTt) STAGE(0, kbase + (kt + 2) * 64);
        COMPUTE(1);
        __syncthreads();
    }

    // cross-wave reduce over tile-key-halves
    float* red = (float*)ldsc;   // 4096 floats
    if (kh == 1) {
        #pragma unroll
        for (int r = 0; r < 16; ++r) {
            int q = (r & 3) + 8 * (r >> 2) + 4 * h;
            red[qh * 2048 + q * 64 + c31]      = xacc0[r];
            red[qh * 2048 + q * 64 + 32 + c31] = xacc1[r];
        }
    }
    __syncthreads();
    if (kh == 0) {
        #pragma unroll
        for (int r = 0; r < 16; ++r) {
            int q = (r & 3) + 8 * (r >> 2) + 4 * h;
            float x0 = xacc0[r] + red[qh * 2048 + q * 64 + c31];
            float x1 = xacc1[r] + red[qh * 2048 + q * 64 + 32 + c31];
            int qg = q0 + qh * 32 + q;
            if (PARTIAL) {
                float* pp = outp + ((size_t)((blk & 1) * NBH + bh) * S + qg) * D;
                pp[c31]      = x0;
                pp[32 + c31] = x1;
            } else {
                float mq = (float)mask[b * S + qg];
                x0 *= mq; x1 *= mq;
                float ss = x0 * x0 + x1 * x1;
                #pragma unroll
                for (int m = 1; m <= 16; m <<= 1) ss += __shfl_xor(ss, m, 64);
                float sc = rsqrtf(ss + 1e-6f);
                float* op = outp + ((size_t)bh * S + qg) * D;
                op[c31]      = x0 * sc;
                op[32 + c31] = x1 * sc;
            }
        }
    }
}

// Pass 2: sum key-half partials, apply query mask, L2-normalize, store fp32.
__global__ __launch_bounds__(256) void combine_norm(const float* __restrict__ P,
                                                    const int* __restrict__ mask,
                                                    float* __restrict__ out) {
    size_t row = (size_t)blockIdx.x * 4 + (threadIdx.x >> 6);
    int lane = threadIdx.x & 63;
    size_t i = row * 64 + lane;
    float x = P[i] + P[(size_t)NBH * S * D + i];
    int bh = (int)(row >> 11);          // S = 2048
    int sidx = (int)(row & 2047);
    int b = bh / 12;
    x *= (float)mask[b * S + sidx];
    float ss = x * x;
    #pragma unroll
    for (int m = 1; m <= 32; m <<= 1) ss += __shfl_xor(ss, m, 64);
    out[i] = x * rsqrtf(ss + 1e-6f);
}

extern "C" void kernel_launch(void* const* d_in, const int* in_sizes, int n_in,
                              void* d_out, int out_size, void* d_ws, size_t ws_size,
                              hipStream_t stream) {
    const float* Q    = (const float*)d_in[0];
    const float* K    = (const float*)d_in[1];
    const float* V    = (const float*)d_in[2];
    const int*   mask = (const int*)d_in[3];
    const int*   hlen = (const int*)d_in[4];
    float*       out  = (float*)d_out;

    __hip_bfloat16* Qn = (__hip_bfloat16*)d_ws;
    __hip_bfloat16* Kn = Qn + (size_t)NBH * S * D;
    __hip_bfloat16* Vt = Kn + (size_t)NBH * S * D;
    float* Pbuf = (float*)((char*)d_ws + 3ull * NBH * S * D * 2);  // 2x partials fp32

    const size_t ws_need = 3ull * NBH * S * D * 2 + 2ull * NBH * S * D * 4;

    norm_qk<<<2 * NBH * S / 4, 256, 0, stream>>>(Q, K, Qn, Kn);
    transpose_v<<<NBH * 32, 256, 0, stream>>>(V, mask, Vt);
    if (ws_size >= ws_need) {
        yoso_main<true><<<NBH * 64, 256, 0, stream>>>(Qn, Kn, Vt, mask, hlen, Pbuf);
        combine_norm<<<NBH * S / 4, 256, 0, stream>>>(Pbuf, mask, out);
    } else {
        yoso_main<false><<<NBH * 32, 256, 0, stream>>>(Qn, Kn, Vt, mask, hlen, out);
    }
}